// Round 4
// baseline (126.550 us; speedup 1.0000x reference)
//
#include <hip/hip_runtime.h>
#include <math.h>

#define B 4
#define T 4096
#define H 2048
#define NC 128
#define C  (T / NC)        // 32 timesteps per chunk
#define PF 8               // prefetch depth (timesteps)
#define THREADS 512        // 512 threads x f4 = 2048 channels = full row

typedef float f4 __attribute__((ext_vector_type(4)));

// ---------------------------------------------------------------------------
// Phase 1: per-chunk local scan from zero state.
// Block = (b, chunk c), covers ALL H channels -> fully contiguous streaming:
// each block reads two 256 KB extents (k chunk, v chunk) front to back.
// Register ring buffer PF timesteps deep, fully unrolled (static indices).
// ---------------------------------------------------------------------------
__global__ __launch_bounds__(THREADS)
void wkv_local_kernel(const float* __restrict__ kg,
                      const float* __restrict__ vg,
                      const float* __restrict__ td,
                      float* __restrict__ loc_a,
                      float* __restrict__ loc_b) {
    int c   = blockIdx.x & (NC - 1);
    int b   = blockIdx.x >> 7;                 // / NC (=128)
    int tid = threadIdx.x;
    const int S = H / 4;                        // f4 per timestep row

    const f4* kp = (const f4*)(kg + ((size_t)b * T + (size_t)c * C) * H) + tid;
    const f4* vp = (const f4*)(vg + ((size_t)b * T + (size_t)c * C) * H) + tid;

    f4 tdv = ((const f4*)td)[tid];
    f4 ew;
#pragma unroll
    for (int q = 0; q < 4; ++q) ew[q] = expf(-expf(tdv[q]));

    f4 a = {0.f, 0.f, 0.f, 0.f}, bb = {0.f, 0.f, 0.f, 0.f};

    f4 kb[PF], vb[PF];
#pragma unroll
    for (int j = 0; j < PF; ++j) { kb[j] = kp[(size_t)j * S]; vb[j] = vp[(size_t)j * S]; }

#pragma unroll
    for (int t = 0; t < C; ++t) {
        f4 kk = kb[t & (PF - 1)];
        f4 vv = vb[t & (PF - 1)];
        if (t + PF < C) {
            kb[t & (PF - 1)] = kp[(size_t)(t + PF) * S];
            vb[t & (PF - 1)] = vp[(size_t)(t + PF) * S];
        }
#pragma unroll
        for (int q = 0; q < 4; ++q) {
            float ek = expf(kk[q]);
            a[q]  = ew[q] * a[q]  + ek * vv[q];
            bb[q] = ew[q] * bb[q] + ek;
        }
    }

    size_t o = ((size_t)c * B + b) * (H / 4) + tid;
    ((f4*)loc_a)[o] = a;
    ((f4*)loc_b)[o] = bb;
}

// ---------------------------------------------------------------------------
// Phase 2: carry scan across chunks per (b,h); locals -> exclusive carries;
// final (a,b) states to out.
// ---------------------------------------------------------------------------
__global__ __launch_bounds__(256)
void wkv_carry_kernel(const float* __restrict__ time_decay,
                      float* __restrict__ loc_a,
                      float* __restrict__ loc_b,
                      float* __restrict__ out) {
    int idx = blockIdx.x * 256 + threadIdx.x;   // 0 .. B*H-1
    int b = idx / H;
    int h = idx % H;

    float ew  = expf(-expf(time_decay[h]));
    float ewC = powf(ew, (float)C);

    float Sa = 0.0f, Sb = 0.0f;
    for (int c = 0; c < NC; ++c) {
        size_t o = ((size_t)c * B + b) * H + h;
        float la = loc_a[o];
        float lb = loc_b[o];
        loc_a[o] = Sa;
        loc_b[o] = Sb;
        Sa = ewC * Sa + la;
        Sb = ewC * Sb + lb;
    }
    out[(size_t)B * T * H + (size_t)b * H + h] = Sa;
    out[(size_t)B * T * H + (size_t)B * H + (size_t)b * H + h] = Sb;
}

// ---------------------------------------------------------------------------
// Phase 3: replay each chunk from its exclusive carry, emit wkv outputs.
// Same contiguous streaming structure; nontemporal f4 output stores.
// ---------------------------------------------------------------------------
__global__ __launch_bounds__(THREADS)
void wkv_emit_kernel(const float* __restrict__ kg,
                     const float* __restrict__ vg,
                     const float* __restrict__ td,
                     const float* __restrict__ tf,
                     const float* __restrict__ loc_a,
                     const float* __restrict__ loc_b,
                     float* __restrict__ out) {
    int c   = blockIdx.x & (NC - 1);
    int b   = blockIdx.x >> 7;
    int tid = threadIdx.x;
    const int S = H / 4;

    const f4* kp = (const f4*)(kg + ((size_t)b * T + (size_t)c * C) * H) + tid;
    const f4* vp = (const f4*)(vg + ((size_t)b * T + (size_t)c * C) * H) + tid;
    f4*       op = (f4*)(out + ((size_t)b * T + (size_t)c * C) * H) + tid;

    f4 tdv = ((const f4*)td)[tid];
    f4 tfv = ((const f4*)tf)[tid];
    f4 ew, eu;
#pragma unroll
    for (int q = 0; q < 4; ++q) {
        ew[q] = expf(-expf(tdv[q]));
        eu[q] = expf(tfv[q]);
    }

    size_t o = ((size_t)c * B + b) * (H / 4) + tid;
    f4 a  = ((const f4*)loc_a)[o];
    f4 bb = ((const f4*)loc_b)[o];

    f4 kb[PF], vb[PF];
#pragma unroll
    for (int j = 0; j < PF; ++j) { kb[j] = kp[(size_t)j * S]; vb[j] = vp[(size_t)j * S]; }

#pragma unroll
    for (int t = 0; t < C; ++t) {
        f4 kk = kb[t & (PF - 1)];
        f4 vv = vb[t & (PF - 1)];
        if (t + PF < C) {
            kb[t & (PF - 1)] = kp[(size_t)(t + PF) * S];
            vb[t & (PF - 1)] = vp[(size_t)(t + PF) * S];
        }
        f4 r;
#pragma unroll
        for (int q = 0; q < 4; ++q) {
            float ek  = expf(kk[q]);
            float euk = ek * eu[q];
            r[q] = (a[q] + euk * vv[q]) / (bb[q] + euk + 1e-8f);
            a[q]  = ew[q] * a[q]  + ek * vv[q];
            bb[q] = ew[q] * bb[q] + ek;
        }
        __builtin_nontemporal_store(r, op + (size_t)t * S);
    }
}

extern "C" void kernel_launch(void* const* d_in, const int* in_sizes, int n_in,
                              void* d_out, int out_size, void* d_ws, size_t ws_size,
                              hipStream_t stream) {
    const float* k  = (const float*)d_in[0];
    const float* v  = (const float*)d_in[1];
    const float* td = (const float*)d_in[2];
    const float* tf = (const float*)d_in[3];
    float* out      = (float*)d_out;

    float* loc_a = (float*)d_ws;                 // 2 * B*H*NC * 4 B = 8 MB (fits)
    float* loc_b = loc_a + (size_t)B * H * NC;

    dim3 grid1(B * NC);                          // 512 blocks, 512 threads
    dim3 grid2((B * H) / 256);                   // 32 blocks, 256 threads

    wkv_local_kernel<<<grid1, dim3(THREADS), 0, stream>>>(k, v, td, loc_a, loc_b);
    wkv_carry_kernel<<<grid2, dim3(256), 0, stream>>>(td, loc_a, loc_b, out);
    wkv_emit_kernel<<<grid1, dim3(THREADS), 0, stream>>>(k, v, td, tf, loc_a, loc_b, out);
}

// Round 5
// 89.183 us; speedup vs baseline: 1.4190x; 1.4190x over previous
//
#include <hip/hip_runtime.h>
#include <math.h>
#include <stdint.h>

#define B 4
#define T 4096
#define H 2048
#define TT 256            // timesteps per LDS tile
#define NT (T / TT)       // 16 tiles
#define NBAND (H / 32)    // 64 bands of 32 channels
#define THREADS 512
#define NSUB 16           // subchunks per tile
#define SUBL (TT / NSUB)  // 16 steps per subchunk

typedef const __attribute__((address_space(1))) uint32_t* gas_ptr;
typedef __attribute__((address_space(3))) uint32_t* las_ptr;

// Stage 8 timesteps x 32 channels (8 rows x 128B = 1KB) global -> LDS.
// Lane l supplies row (l>>3), bytes (l&7)*16 .. +16; LDS dest linear at lane*16.
// Each 128B row = exactly one cache line; bands are disjoint -> each HBM line
// is fetched exactly once chip-wide.
__device__ __forceinline__ void stage8(const float* gbase, float* lbase, int lane) {
    __builtin_amdgcn_global_load_lds(
        (gas_ptr)(const void*)(gbase + (lane >> 3) * H + (lane & 7) * 4),
        (las_ptr)(void*)lbase, 16, 0, 0);
}

// ---------------------------------------------------------------------------
// Fused WKV: block = (batch b, band of 32 channels), owns all T=4096 steps.
// k,v read ONCE from HBM; per-tile in-LDS chunked scan (locals -> exclusive
// carry -> emit); running state carried in registers of threads 0..31.
// ---------------------------------------------------------------------------
__global__ __launch_bounds__(THREADS)
void wkv_fused_kernel(const float* __restrict__ kg,
                      const float* __restrict__ vg,
                      const float* __restrict__ td,
                      const float* __restrict__ tf,
                      float* __restrict__ out) {
    __shared__ float lk[2][TT][32];     // 2 x 32KB
    __shared__ float lv[2][TT][32];     // 2 x 32KB
    __shared__ float sa[NSUB][32];
    __shared__ float sb[NSUB][32];

    int band = blockIdx.x & (NBAND - 1);
    int b    = blockIdx.x >> 6;          // / NBAND
    int tid  = threadIdx.x;
    int lane = tid & 63;
    int wv   = tid >> 6;                 // wave 0..7
    int ch   = tid & 31;
    int sub  = tid >> 5;                 // 0..15

    const float* kbase = kg + (size_t)b * T * H + band * 32;
    const float* vbase = vg + (size_t)b * T * H + band * 32;
    float* obase       = out + (size_t)b * T * H + band * 32;

    int h = band * 32 + ch;
    float ew = expf(-expf(td[h]));
    float eu = expf(tf[h]);
    float e2 = ew * ew, e4 = e2 * e2, e8 = e4 * e4;
    float ewL = e8 * e8;                 // ew^SUBL (SUBL=16)

    float Ra = 0.f, Rb = 0.f;            // running state (threads 0..31)

    // each of 8 waves issues 4 k-rows-groups + 4 v-rows-groups = 8 loads/tile
#define ISSUE(tile, bufi)                                                   \
    {                                                                       \
        _Pragma("unroll")                                                   \
        for (int ii = 0; ii < 4; ++ii) {                                    \
            int i = wv * 4 + ii;                                            \
            stage8(kbase + ((size_t)(tile) * TT + 8 * i) * H,               \
                   &lk[bufi][8 * i][0], lane);                              \
            stage8(vbase + ((size_t)(tile) * TT + 8 * i) * H,               \
                   &lv[bufi][8 * i][0], lane);                              \
        }                                                                   \
    }

    ISSUE(0, 0);
    for (int j = 0; j < NT; ++j) {
        const int cur = j & 1;
        if (j + 1 < NT) {
            ISSUE(j + 1, cur ^ 1);
            // 8 newest (tile j+1) may stay in flight; tile j's 8 are done.
            asm volatile("s_waitcnt vmcnt(8)" ::: "memory");
        } else {
            asm volatile("s_waitcnt vmcnt(0)" ::: "memory");
        }
        __builtin_amdgcn_s_barrier();

        // Phase A: local scan of this thread's 16-step subchunk (from zero)
        float la = 0.f, lb = 0.f;
#pragma unroll
        for (int i = 0; i < SUBL; ++i) {
            int t = sub * SUBL + i;
            float kk = lk[cur][t][ch];
            float vv = lv[cur][t][ch];
            float ek = expf(kk);
            la = ew * la + ek * vv;
            lb = ew * lb + ek;
        }
        sa[sub][ch] = la;
        sb[sub][ch] = lb;
        asm volatile("s_waitcnt lgkmcnt(0)" ::: "memory");
        __builtin_amdgcn_s_barrier();

        // Phase B: exclusive carry across the 16 subchunks (threads 0..31)
        if (tid < 32) {
            float ra = Ra, rb = Rb;
#pragma unroll
            for (int s = 0; s < NSUB; ++s) {
                float ta = sa[s][ch];
                float tb = sb[s][ch];
                sa[s][ch] = ra;
                sb[s][ch] = rb;
                ra = ewL * ra + ta;
                rb = ewL * rb + tb;
            }
            Ra = ra; Rb = rb;
        }
        asm volatile("s_waitcnt lgkmcnt(0)" ::: "memory");
        __builtin_amdgcn_s_barrier();

        // Phase C: replay subchunk from exclusive carry, emit outputs
        float a2 = sa[sub][ch];
        float b2 = sb[sub][ch];
#pragma unroll
        for (int i = 0; i < SUBL; ++i) {
            int t = sub * SUBL + i;
            float kk = lk[cur][t][ch];
            float vv = lv[cur][t][ch];
            float ek  = expf(kk);
            float euk = ek * eu;
            float r   = (a2 + euk * vv) / (b2 + euk + 1e-8f);
            __builtin_nontemporal_store(r, obase + ((size_t)j * TT + t) * H + ch);
            a2 = ew * a2 + ek * vv;
            b2 = ew * b2 + ek;
        }
        __builtin_amdgcn_s_barrier();    // all LDS reads of buf `cur` done
    }

    // final states: outputs 1 (a) and 2 (b), each (B, H)
    if (tid < 32) {
        size_t so = (size_t)B * T * H;
        out[so + (size_t)b * H + h] = Ra;
        out[so + (size_t)B * H + (size_t)b * H + h] = Rb;
    }
}

extern "C" void kernel_launch(void* const* d_in, const int* in_sizes, int n_in,
                              void* d_out, int out_size, void* d_ws, size_t ws_size,
                              hipStream_t stream) {
    const float* k  = (const float*)d_in[0];
    const float* v  = (const float*)d_in[1];
    const float* td = (const float*)d_in[2];
    const float* tf = (const float*)d_in[3];
    float* out      = (float*)d_out;

    dim3 grid(B * NBAND);                // 256 blocks = 1 per CU
    wkv_fused_kernel<<<grid, dim3(THREADS), 0, stream>>>(k, v, td, tf, out);
}

// Round 6
// 82.229 us; speedup vs baseline: 1.5390x; 1.0846x over previous
//
#include <hip/hip_runtime.h>
#include <math.h>
#include <stdint.h>

#define B 4
#define T 4096
#define H 2048
#define TT 256            // timesteps per LDS tile
#define NT (T / TT)       // 16 tiles
#define NBAND (H / 32)    // 64 bands of 32 channels
#define THREADS 512
#define NSUB 16           // subchunks per tile
#define SUBL (TT / NSUB)  // 16 steps per subchunk

typedef const __attribute__((address_space(1))) uint32_t* gas_ptr;
typedef __attribute__((address_space(3))) uint32_t* las_ptr;

// Stage 8 timesteps x 32 channels (8 rows x 128B = 1KB) global -> LDS.
// Each 128B row = exactly one cache line; bands disjoint -> each HBM line
// fetched exactly once chip-wide.
__device__ __forceinline__ void stage8(const float* gbase, float* lbase, int lane) {
    __builtin_amdgcn_global_load_lds(
        (gas_ptr)(const void*)(gbase + (lane >> 3) * H + (lane & 7) * 4),
        (las_ptr)(void*)lbase, 16, 0, 0);
}

// ---------------------------------------------------------------------------
// Fused WKV: block = (batch b, band of 32 channels), owns all T=4096 steps.
// k,v read ONCE. Per tile: A) per-thread 16-step local scan, writing ek/ekv
// back into the LDS slots; B) all-thread redundant register scan across the
// 16 subchunk partials (no serial section, no divergence); C) emit from the
// exclusive carry with zero expf (uses stored ek/ekv) and v_rcp division.
// ---------------------------------------------------------------------------
__global__ __launch_bounds__(THREADS)
void wkv_fused_kernel(const float* __restrict__ kg,
                      const float* __restrict__ vg,
                      const float* __restrict__ td,
                      const float* __restrict__ tf,
                      float* __restrict__ out) {
    __shared__ float lk[2][TT][32];     // 2 x 32KB   (k -> ek after phase A)
    __shared__ float lv[2][TT][32];     // 2 x 32KB   (v -> ek*v after phase A)
    __shared__ float sa[NSUB][32];
    __shared__ float sb[NSUB][32];

    int band = blockIdx.x & (NBAND - 1);
    int b    = blockIdx.x >> 6;          // / NBAND
    int tid  = threadIdx.x;
    int lane = tid & 63;
    int wv   = tid >> 6;                 // wave 0..7
    int ch   = tid & 31;
    int sub  = tid >> 5;                 // 0..15

    const float* kbase = kg + (size_t)b * T * H + band * 32;
    const float* vbase = vg + (size_t)b * T * H + band * 32;
    float* obase       = out + (size_t)b * T * H + band * 32;

    int h = band * 32 + ch;
    float ew = expf(-expf(td[h]));
    float eu = expf(tf[h]);

    // ewL = ew^SUBL (=ew^16); powers for the cross-subchunk scan
    float e2 = ew * ew, e4 = e2 * e2, e8 = e4 * e4;
    float ewL  = e8 * e8;                // ew^16
    float el2  = ewL * ewL;              // ew^32
    float el4  = el2 * el2;              // ew^64
    float el8  = el4 * el4;              // ew^128
    float ewT  = el8 * el8;              // ew^256 = ew^TT
    float ewpow = 1.0f;                  // ewL^sub
    if (sub & 1) ewpow *= ewL;
    if (sub & 2) ewpow *= el2;
    if (sub & 4) ewpow *= el4;
    if (sub & 8) ewpow *= el8;

    float Ra = 0.f, Rb = 0.f;            // running state (redundant per thread)

    // each of 8 waves issues 4 k-row-groups + 4 v-row-groups = 8 loads/tile
#define ISSUE(tile, bufi)                                                   \
    {                                                                       \
        _Pragma("unroll")                                                   \
        for (int ii = 0; ii < 4; ++ii) {                                    \
            int i = wv * 4 + ii;                                            \
            stage8(kbase + ((size_t)(tile) * TT + 8 * i) * H,               \
                   &lk[bufi][8 * i][0], lane);                              \
            stage8(vbase + ((size_t)(tile) * TT + 8 * i) * H,               \
                   &lv[bufi][8 * i][0], lane);                              \
        }                                                                   \
    }

    ISSUE(0, 0);
    for (int j = 0; j < NT; ++j) {
        const int cur = j & 1;
        if (j + 1 < NT) {
            ISSUE(j + 1, cur ^ 1);
            asm volatile("s_waitcnt vmcnt(8)" ::: "memory");   // tile j done
        } else {
            asm volatile("s_waitcnt vmcnt(0)" ::: "memory");
        }
        __builtin_amdgcn_s_barrier();

        // Phase A: local scan of own 16-step subchunk; store ek / ek*v back
        float la = 0.f, lb = 0.f;
#pragma unroll
        for (int i = 0; i < SUBL; ++i) {
            int t = sub * SUBL + i;
            float kk = lk[cur][t][ch];
            float vv = lv[cur][t][ch];
            float ek  = expf(kk);
            float ekv = ek * vv;
            lk[cur][t][ch] = ek;
            lv[cur][t][ch] = ekv;
            la = ew * la + ekv;
            lb = ew * lb + ek;
        }
        sa[sub][ch] = la;
        sb[sub][ch] = lb;
        asm volatile("s_waitcnt lgkmcnt(0)" ::: "memory");
        __builtin_amdgcn_s_barrier();

        // Phase B: every thread scans the 16 partials of its channel.
        // prefix pa/pb = sum_{s<sub} ewL^{sub-1-s} L_s ; total ta/tb for R.
        float pa = 0.f, pb = 0.f, ta = 0.f, tb = 0.f;
#pragma unroll
        for (int s = 0; s < NSUB; ++s) {
            float xa = sa[s][ch];
            float xb = sb[s][ch];
            ta = ewL * ta + xa;
            tb = ewL * tb + xb;
            bool use = (s < sub);
            pa = use ? (ewL * pa + xa) : pa;
            pb = use ? (ewL * pb + xb) : pb;
        }
        float a2 = ewpow * Ra + pa;      // exclusive carry into this subchunk
        float b2 = ewpow * Rb + pb;
        Ra = ewT * Ra + ta;              // advance running state one tile
        Rb = ewT * Rb + tb;

        // Phase C: emit (no expf; ek/ekv from LDS; fast reciprocal)
#pragma unroll
        for (int i = 0; i < SUBL; ++i) {
            int t = sub * SUBL + i;
            float ek  = lk[cur][t][ch];
            float ekv = lv[cur][t][ch];
            float num = a2 + eu * ekv;
            float den = b2 + eu * ek + 1e-8f;
            float inv;
            asm("v_rcp_f32 %0, %1" : "=v"(inv) : "v"(den));
            float r = num * inv;
            __builtin_nontemporal_store(r, obase + ((size_t)j * TT + t) * H + ch);
            a2 = ew * a2 + ekv;
            b2 = ew * b2 + ek;
        }
        __builtin_amdgcn_s_barrier();    // all LDS reads of buf `cur` done
    }

    // final states: outputs 1 (a) and 2 (b), each (B, H)
    if (tid < 32) {
        size_t so = (size_t)B * T * H;
        out[so + (size_t)b * H + h] = Ra;
        out[so + (size_t)B * H + (size_t)b * H + h] = Rb;
    }
}

extern "C" void kernel_launch(void* const* d_in, const int* in_sizes, int n_in,
                              void* d_out, int out_size, void* d_ws, size_t ws_size,
                              hipStream_t stream) {
    const float* k  = (const float*)d_in[0];
    const float* v  = (const float*)d_in[1];
    const float* td = (const float*)d_in[2];
    const float* tf = (const float*)d_in[3];
    float* out      = (float*)d_out;

    dim3 grid(B * NBAND);                // 256 blocks = 1 per CU
    wkv_fused_kernel<<<grid, dim3(THREADS), 0, stream>>>(k, v, td, tf, out);
}

// Round 7
// 79.717 us; speedup vs baseline: 1.5875x; 1.0315x over previous
//
#include <hip/hip_runtime.h>
#include <math.h>
#include <stdint.h>

#define B 4
#define T 4096
#define H 2048
#define TT 256            // timesteps per LDS tile
#define NT (T / TT)       // 16 tiles
#define NBAND (H / 32)    // 64 bands of 32 channels
#define THREADS 1024      // 16 waves/CU
#define NSUB 32           // subchunks per tile (THREADS / 32 channels)
#define SUBL (TT / NSUB)  // 8 steps per subchunk

typedef const __attribute__((address_space(1))) uint32_t* gas_ptr;
typedef __attribute__((address_space(3))) uint32_t* las_ptr;

// Stage 8 timesteps x 32 channels (8 rows x 128B = 1KB) global -> LDS.
// Each 128B row = exactly one cache line; bands disjoint -> each HBM line
// fetched exactly once chip-wide.
__device__ __forceinline__ void stage8(const float* gbase, float* lbase, int lane) {
    __builtin_amdgcn_global_load_lds(
        (gas_ptr)(const void*)(gbase + (lane >> 3) * H + (lane & 7) * 4),
        (las_ptr)(void*)lbase, 16, 0, 0);
}

// ---------------------------------------------------------------------------
// Fused WKV: block = (batch b, band of 32 channels), owns all T=4096 steps.
// k,v read ONCE. Per tile: A) per-thread 8-step local scan (fast __expf),
// writing ek/ek*v back into the LDS slots; B) all-thread single-chain scan
// over the 32 packed float2 partials with a cndmask capture at s==sub;
// C) emit from the exclusive carry with zero expf and v_rcp division.
// vmcnt accounting includes phase-C stores so we never force a store drain:
// per wave per tile the queue is [L_j(4) | S_{j-1}(8) | L_{j+1}(4)].
// ---------------------------------------------------------------------------
__global__ __launch_bounds__(THREADS)
void wkv_fused_kernel(const float* __restrict__ kg,
                      const float* __restrict__ vg,
                      const float* __restrict__ td,
                      const float* __restrict__ tf,
                      float* __restrict__ out) {
    __shared__ float  lk[2][TT][32];    // 2 x 32KB   (k -> ek after phase A)
    __shared__ float  lv[2][TT][32];    // 2 x 32KB   (v -> ek*v after phase A)
    __shared__ float2 sab[NSUB][32];    // packed (la, lb) partials, 8KB

    int band = blockIdx.x & (NBAND - 1);
    int b    = blockIdx.x >> 6;          // / NBAND
    int tid  = threadIdx.x;
    int lane = tid & 63;
    int wv   = tid >> 6;                 // wave 0..15
    int ch   = tid & 31;
    int sub  = tid >> 5;                 // 0..31

    const float* kbase = kg + (size_t)b * T * H + band * 32;
    const float* vbase = vg + (size_t)b * T * H + band * 32;
    float* obase       = out + (size_t)b * T * H + band * 32;

    int h = band * 32 + ch;
    float ew = expf(-expf(td[h]));
    float eu = expf(tf[h]);

    // powers of ew: ewL = ew^SUBL (=ew^8); ladder up to ew^256
    float e2 = ew * ew, e4 = e2 * e2;
    float ewL  = e4 * e4;                // ew^8
    float l2   = ewL * ewL;              // ew^16
    float l4   = l2 * l2;                // ew^32
    float l8   = l4 * l4;                // ew^64
    float l16  = l8 * l8;                // ew^128
    float ewT  = l16 * l16;              // ew^256 = ew^TT
    float ewpow = 1.0f;                  // ewL^sub
    if (sub & 1)  ewpow *= ewL;
    if (sub & 2)  ewpow *= l2;
    if (sub & 4)  ewpow *= l4;
    if (sub & 8)  ewpow *= l8;
    if (sub & 16) ewpow *= l16;

    float Ra = 0.f, Rb = 0.f;            // running state (redundant per thread)

    // 16 waves x (2 k-groups + 2 v-groups) of 8 rows each = whole 256-row tile
#define ISSUE(tile, bufi)                                                   \
    {                                                                       \
        _Pragma("unroll")                                                   \
        for (int ii = 0; ii < 2; ++ii) {                                    \
            int g = wv * 2 + ii;                                            \
            stage8(kbase + ((size_t)(tile) * TT + 8 * g) * H,               \
                   &lk[bufi][8 * g][0], lane);                              \
            stage8(vbase + ((size_t)(tile) * TT + 8 * g) * H,               \
                   &lv[bufi][8 * g][0], lane);                              \
        }                                                                   \
    }

    ISSUE(0, 0);
    for (int j = 0; j < NT; ++j) {
        const int cur = j & 1;
        if (j + 1 < NT) ISSUE(j + 1, cur ^ 1);
        // wait for tile j's 4 loads (oldest) without draining younger stores
        if (j == 0) {
            asm volatile("s_waitcnt vmcnt(4)" ::: "memory");   // [L0|L1]
        } else if (j + 1 < NT) {
            asm volatile("s_waitcnt vmcnt(12)" ::: "memory");  // [Lj|S(8)|Lj+1]
        } else {
            asm volatile("s_waitcnt vmcnt(8)" ::: "memory");   // [Llast|S(8)]
        }
        __builtin_amdgcn_s_barrier();

        // Phase A: local scan of own 8-step subchunk; store ek / ek*v back
        float la = 0.f, lb = 0.f;
#pragma unroll
        for (int i = 0; i < SUBL; ++i) {
            int t = sub * SUBL + i;
            float kk = lk[cur][t][ch];
            float vv = lv[cur][t][ch];
            float ek  = __expf(kk);
            float ekv = ek * vv;
            lk[cur][t][ch] = ek;
            lv[cur][t][ch] = ekv;
            la = ew * la + ekv;
            lb = ew * lb + ek;
        }
        sab[sub][ch] = make_float2(la, lb);
        asm volatile("s_waitcnt lgkmcnt(0)" ::: "memory");
        __builtin_amdgcn_s_barrier();

        // Phase B: single scan chain over 32 partials; capture exclusive
        // prefix when s == sub (before that step's accumulate).
        float ta = 0.f, tb = 0.f, pa = 0.f, pb = 0.f;
#pragma unroll
        for (int s = 0; s < NSUB; ++s) {
            float2 x = sab[s][ch];
            bool cap = (s == sub);
            pa = cap ? ta : pa;
            pb = cap ? tb : pb;
            ta = ewL * ta + x.x;
            tb = ewL * tb + x.y;
        }
        float a2 = ewpow * Ra + pa;      // exclusive carry into this subchunk
        float b2 = ewpow * Rb + pb;
        Ra = ewT * Ra + ta;              // advance running state one tile
        Rb = ewT * Rb + tb;

        // Phase C: emit (no expf; ek/ekv from LDS; fast reciprocal)
#pragma unroll
        for (int i = 0; i < SUBL; ++i) {
            int t = sub * SUBL + i;
            float ek  = lk[cur][t][ch];
            float ekv = lv[cur][t][ch];
            float num = a2 + eu * ekv;
            float den = b2 + eu * ek + 1e-8f;
            float inv;
            asm("v_rcp_f32 %0, %1" : "=v"(inv) : "v"(den));
            float r = num * inv;
            __builtin_nontemporal_store(r, obase + ((size_t)j * TT + t) * H + ch);
            a2 = ew * a2 + ekv;
            b2 = ew * b2 + ek;
        }
        __builtin_amdgcn_s_barrier();    // all LDS reads of buf `cur` done
    }

    // final states: outputs 1 (a) and 2 (b), each (B, H)
    if (tid < 32) {
        size_t so = (size_t)B * T * H;
        out[so + (size_t)b * H + h] = Ra;
        out[so + (size_t)B * H + (size_t)b * H + h] = Rb;
    }
}

extern "C" void kernel_launch(void* const* d_in, const int* in_sizes, int n_in,
                              void* d_out, int out_size, void* d_ws, size_t ws_size,
                              hipStream_t stream) {
    const float* k  = (const float*)d_in[0];
    const float* v  = (const float*)d_in[1];
    const float* td = (const float*)d_in[2];
    const float* tf = (const float*)d_in[3];
    float* out      = (float*)d_out;

    dim3 grid(B * NBAND);                // 256 blocks = 1 per CU
    wkv_fused_kernel<<<grid, dim3(THREADS), 0, stream>>>(k, v, td, tf, out);
}

// Round 8
// 70.074 us; speedup vs baseline: 1.8059x; 1.1376x over previous
//
#include <hip/hip_runtime.h>
#include <math.h>
#include <stdint.h>

#define B 4
#define T 4096
#define H 2048
#define TT 256            // timesteps per LDS tile
#define NT (T / TT)       // 16 tiles
#define NBAND (H / 32)    // 64 bands of 32 channels
#define THREADS 1024      // 16 waves/CU
#define NSUB 32           // subchunks per tile (THREADS / 32 channels)
#define SUBL (TT / NSUB)  // 8 steps per subchunk

typedef const __attribute__((address_space(1))) uint32_t* gas_ptr;
typedef __attribute__((address_space(3))) uint32_t* las_ptr;

// Stage 8 timesteps x 32 channels (8 rows x 128B = 1KB) global -> LDS.
// Each 128B row = exactly one cache line; bands disjoint -> each HBM line
// fetched exactly once chip-wide.
__device__ __forceinline__ void stage8(const float* gbase, float* lbase, int lane) {
    __builtin_amdgcn_global_load_lds(
        (gas_ptr)(const void*)(gbase + (lane >> 3) * H + (lane & 7) * 4),
        (las_ptr)(void*)lbase, 16, 0, 0);
}

// ---------------------------------------------------------------------------
// Fused WKV: block = (batch b, band of 32 channels), owns all T=4096 steps.
// k,v read ONCE. Per tile: A) per-thread 8-step local scan (__expf), keeping
// ek / ek*v in REGISTERS (no LDS write-back); B) all-thread redundant scan
// over the 32 packed float2 partials (cndmask capture at s==sub); C) emit
// from the exclusive carry using the register-resident ek/ekv, v_rcp divide.
// 2 barriers/tile: post-A (sab ready; lk/lv reads done -> buffer reusable)
// and the top-of-loop staging barrier. Counted vmcnt never drains stores:
// per wave per tile the queue is [L_j(4) | S_{j-1}(8) | L_{j+1}(4)].
// ---------------------------------------------------------------------------
__global__ __launch_bounds__(THREADS)
void wkv_fused_kernel(const float* __restrict__ kg,
                      const float* __restrict__ vg,
                      const float* __restrict__ td,
                      const float* __restrict__ tf,
                      float* __restrict__ out) {
    __shared__ float  lk[2][TT][32];    // 2 x 32KB
    __shared__ float  lv[2][TT][32];    // 2 x 32KB
    __shared__ float2 sab[NSUB][32];    // packed (la, lb) partials, 8KB

    int band = blockIdx.x & (NBAND - 1);
    int b    = blockIdx.x >> 6;          // / NBAND
    int tid  = threadIdx.x;
    int lane = tid & 63;
    int wv   = tid >> 6;                 // wave 0..15
    int ch   = tid & 31;
    int sub  = tid >> 5;                 // 0..31

    const float* kbase = kg + (size_t)b * T * H + band * 32;
    const float* vbase = vg + (size_t)b * T * H + band * 32;
    float* obase       = out + (size_t)b * T * H + band * 32;

    int h = band * 32 + ch;
    float ew = expf(-expf(td[h]));
    float eu = expf(tf[h]);

    // powers of ew: ewL = ew^SUBL (=ew^8); ladder up to ew^256
    float e2 = ew * ew, e4 = e2 * e2;
    float ewL  = e4 * e4;                // ew^8
    float l2   = ewL * ewL;              // ew^16
    float l4   = l2 * l2;                // ew^32
    float l8   = l4 * l4;                // ew^64
    float l16  = l8 * l8;                // ew^128
    float ewT  = l16 * l16;              // ew^256 = ew^TT
    float ewpow = 1.0f;                  // ewL^sub
    if (sub & 1)  ewpow *= ewL;
    if (sub & 2)  ewpow *= l2;
    if (sub & 4)  ewpow *= l4;
    if (sub & 8)  ewpow *= l8;
    if (sub & 16) ewpow *= l16;

    float Ra = 0.f, Rb = 0.f;            // running state (redundant per thread)

    // 16 waves x (2 k-groups + 2 v-groups) of 8 rows each = whole 256-row tile
#define ISSUE(tile, bufi)                                                   \
    {                                                                       \
        _Pragma("unroll")                                                   \
        for (int ii = 0; ii < 2; ++ii) {                                    \
            int g = wv * 2 + ii;                                            \
            stage8(kbase + ((size_t)(tile) * TT + 8 * g) * H,               \
                   &lk[bufi][8 * g][0], lane);                              \
            stage8(vbase + ((size_t)(tile) * TT + 8 * g) * H,               \
                   &lv[bufi][8 * g][0], lane);                              \
        }                                                                   \
    }

    ISSUE(0, 0);
    for (int j = 0; j < NT; ++j) {
        const int cur = j & 1;
        if (j + 1 < NT) ISSUE(j + 1, cur ^ 1);
        // wait for tile j's 4 loads (oldest) without draining younger stores
        if (j == 0) {
            asm volatile("s_waitcnt vmcnt(4)" ::: "memory");   // [L0|L1]
        } else if (j + 1 < NT) {
            asm volatile("s_waitcnt vmcnt(12)" ::: "memory");  // [Lj|S(8)|Lj+1]
        } else {
            asm volatile("s_waitcnt vmcnt(8)" ::: "memory");   // [Llast|S(8)]
        }
        __builtin_amdgcn_s_barrier();

        // Phase A: local scan of own 8-step subchunk; ek/ekv stay in registers
        float ek[SUBL], ekv[SUBL];
        float la = 0.f, lb = 0.f;
#pragma unroll
        for (int i = 0; i < SUBL; ++i) {
            int t = sub * SUBL + i;
            float kk = lk[cur][t][ch];
            float vv = lv[cur][t][ch];
            float e  = __expf(kk);
            float ev = e * vv;
            ek[i]  = e;
            ekv[i] = ev;
            la = ew * la + ev;
            lb = ew * lb + e;
        }
        sab[sub][ch] = make_float2(la, lb);
        asm volatile("s_waitcnt lgkmcnt(0)" ::: "memory");
        __builtin_amdgcn_s_barrier();    // sab ready; lk/lv[cur] reads done

        // Phase B: single scan chain over 32 partials; capture exclusive
        // prefix when s == sub (before that step's accumulate).
        float ta = 0.f, tb = 0.f, pa = 0.f, pb = 0.f;
#pragma unroll
        for (int s = 0; s < NSUB; ++s) {
            float2 x = sab[s][ch];
            bool cap = (s == sub);
            pa = cap ? ta : pa;
            pb = cap ? tb : pb;
            ta = ewL * ta + x.x;
            tb = ewL * tb + x.y;
        }
        float a2 = ewpow * Ra + pa;      // exclusive carry into this subchunk
        float b2 = ewpow * Rb + pb;
        Ra = ewT * Ra + ta;              // advance running state one tile
        Rb = ewT * Rb + tb;

        // Phase C: emit straight from registers (no LDS, no expf)
#pragma unroll
        for (int i = 0; i < SUBL; ++i) {
            int t = sub * SUBL + i;
            float num = a2 + eu * ekv[i];
            float den = b2 + eu * ek[i] + 1e-8f;
            float inv;
            asm("v_rcp_f32 %0, %1" : "=v"(inv) : "v"(den));
            float r = num * inv;
            __builtin_nontemporal_store(r, obase + ((size_t)j * TT + t) * H + ch);
            a2 = ew * a2 + ekv[i];
            b2 = ew * b2 + ek[i];
        }
        // no barrier needed: buffer `cur` reads finished before post-A barrier
    }

    // final states: outputs 1 (a) and 2 (b), each (B, H)
    if (tid < 32) {
        size_t so = (size_t)B * T * H;
        out[so + (size_t)b * H + h] = Ra;
        out[so + (size_t)B * H + (size_t)b * H + h] = Rb;
    }
}

extern "C" void kernel_launch(void* const* d_in, const int* in_sizes, int n_in,
                              void* d_out, int out_size, void* d_ws, size_t ws_size,
                              hipStream_t stream) {
    const float* k  = (const float*)d_in[0];
    const float* v  = (const float*)d_in[1];
    const float* td = (const float*)d_in[2];
    const float* tf = (const float*)d_in[3];
    float* out      = (float*)d_out;

    dim3 grid(B * NBAND);                // 256 blocks = 1 per CU
    wkv_fused_kernel<<<grid, dim3(THREADS), 0, stream>>>(k, v, td, tf, out);
}